// Round 22
// baseline (140.043 us; speedup 1.0000x reference)
//
#include <hip/hip_runtime.h>

// NeighConv: B=2, C=256, N=4096, K=16
// Pipeline (SINGLE gram sweep; 3 dispatches):
//  1) prep_kernel:    per 64-point block: transpose x -> xt fp32 + xh fp16
//                     (4 channel-tiles through LDS) AND sq32/sq64 norms
//                     (fp64 per-lane partials + wave butterflies);
//                     z==2 branch: Wh fp16 (8 rows/block)
//  2) distyh_kernel:  double-buffered 64KB LDS; jt<32: MFMA gram tile + top-4
//                     epilogue (V^T->LDS scan); jt>=32: K-loop vs Wh -> Yh
//  3) cmf_kernel:     per query (one wave): threshold-collect -> fp64 re-rank
//                     -> top-16+weights in LDS -> weighted-max epilogue -> out

#define B_ 2
#define C_ 256
#define N_ 4096
#define K_ 16
#define SCAP 128
#define INF_F 3.0e38f

typedef _Float16 f16x8 __attribute__((ext_vector_type(8)));
typedef _Float16 f16x4 __attribute__((ext_vector_type(4)));
typedef float    f32x4 __attribute__((ext_vector_type(4)));

// async global->LDS, 16B per lane; LDS dest wave-uniform base + lane*16
#define GL16(gp, lp)                                                        \
    __builtin_amdgcn_global_load_lds(                                       \
        (const __attribute__((address_space(1))) void*)(gp),                \
        (__attribute__((address_space(3))) void*)(lp), 16, 0, 0)

#define LGKM0()  asm volatile("s_waitcnt lgkmcnt(0)" ::: "memory")
#define SCHED0() __builtin_amdgcn_sched_barrier(0)

// ---------------- 1) prep: transpose + norms; z==2: W -> Wh ----------------
// z<2: block = 64 points (i0..i0+63), loops 4 channel-tiles of 64.
// Thread (tx,ty): handles channel c0+tx of rows r in {ty, ty+4, .., ty+60}.
// Wave ty computes 16 point-norms via fp64 butterflies at the end.
__global__ void prep_kernel(const float* __restrict__ x, float* __restrict__ xt,
                            _Float16* __restrict__ xh,
                            const float* __restrict__ W, _Float16* __restrict__ Wh,
                            float* __restrict__ sq32, double* __restrict__ sq64) {
    int tid = threadIdx.x;
    if (blockIdx.z == 2) {                            // Wh branch: 8 rows/block
        int r0 = blockIdx.x << 3;
        #pragma unroll
        for (int u = 0; u < 8; ++u) {
            int r = r0 + u;
            float v = (r < 256) ? W[(size_t)r * 512 + tid]
                                : W[(size_t)(r - 256) * 512 + 256 + tid];
            Wh[(size_t)r * 256 + tid] = (_Float16)v;
        }
        return;
    }
    __shared__ float tile[64][65];
    int i0 = blockIdx.x * 64;
    int b  = blockIdx.z;
    const float* xb = x + ((size_t)b << 20);
    float*    xtb = xt + ((size_t)b << 20);
    _Float16* xhb = xh + ((size_t)b << 20);
    int tx = tid & 63, ty = tid >> 6;

    double pp[16];
    #pragma unroll
    for (int ri = 0; ri < 16; ++ri) pp[ri] = 0.0;

    for (int ct = 0; ct < 4; ++ct) {
        int c0 = ct << 6;
        __syncthreads();                               // tile reusable
        for (int r = ty; r < 64; r += 4)
            tile[r][tx] = xb[(size_t)(c0 + r) * N_ + i0 + tx];
        __syncthreads();
        #pragma unroll
        for (int ri = 0; ri < 16; ++ri) {
            int r = ty + ri * 4;
            float v = tile[tx][r];
            xtb[(size_t)(i0 + r) * C_ + c0 + tx] = v;
            xhb[(size_t)(i0 + r) * C_ + c0 + tx] = (_Float16)v;
            pp[ri] = fma((double)v, (double)v, pp[ri]);
        }
    }

    // wave ty: reduce 16 point-norms (rows ty, ty+4, .., ty+60)
    int bN = b << 12;
    #pragma unroll
    for (int ri = 0; ri < 16; ++ri) {
        double s = pp[ri];
        #pragma unroll
        for (int m = 1; m < 64; m <<= 1) s += __shfl_xor(s, m);
        if (tx == 0) {
            int p = bN + i0 + ty + ri * 4;
            sq64[p] = s;
            sq32[p] = (float)s;
        }
    }
}

// ---------------- 2) fused gram sweep + Yh GEMM (double-buffered, 64KB LDS) ----------------
// grid (36, 32, 2). jt<32: gram tile (128i x 128j) + per-tile top-4 epilogue.
// jt>=32: B = Wh rows (jt-32)*128.., epilogue = bias add + Yh store.
// Conflict-free swizzle (128B rows): byte cb of row r at cb ^ ((r&7)<<4),
// applied to the global SOURCE (gload_lds writes linearly) and to ds_reads.
__launch_bounds__(256, 2)
__global__ void distyh_kernel(const _Float16* __restrict__ xh,
                              const _Float16* __restrict__ Wh,
                              const float* __restrict__ sq32,
                              const float* __restrict__ bias,
                              float* __restrict__ t4v,
                              unsigned short* __restrict__ t4j,
                              _Float16* __restrict__ Yh) {
    __shared__ alignas(16) _Float16 As[2][128][64];
    __shared__ alignas(16) _Float16 Bs[2][128][64];

    int jt = blockIdx.x, it = blockIdx.y, b = blockIdx.z;
    int tid = threadIdx.x;
    int w = tid >> 6, l = tid & 63;
    int wr = w >> 1, wc = w & 1;
    int lr = l & 15, lg = l >> 4;
    const _Float16* xb = xh + ((size_t)b << 20);
    bool isY = jt >= 32;
    int rA0 = it * 128;
    const _Float16* bsrc = isY ? (Wh + (size_t)(jt - 32) * 128 * C_)
                               : (xb + (size_t)(jt * 128) * C_);

    int rsub = l >> 3;                          // 0..7
    int cbyte = (l & 7) << 4;                   // 0..112 bytes

    auto STAGE = [&](int bf, int k0) {
        #pragma unroll
        for (int tt = 0; tt < 4; ++tt) {
            int rloc = w * 32 + tt * 8 + rsub;                 // 0..127
            int srch = (cbyte ^ ((rloc & 7) << 4)) >> 1;       // halfs
            GL16(xb + (size_t)(rA0 + rloc) * C_ + k0 + srch, &As[bf][w * 32 + tt * 8][0]);
            GL16(bsrc + (size_t)rloc * C_ + k0 + srch, &Bs[bf][w * 32 + tt * 8][0]);
        }
    };

    f32x4 acc[4][4];
    #pragma unroll
    for (int mi = 0; mi < 4; ++mi)
        #pragma unroll
        for (int ni = 0; ni < 4; ++ni)
            acc[mi][ni] = (f32x4){0.f, 0.f, 0.f, 0.f};

    STAGE(0, 0);
    __syncthreads();
    #pragma unroll
    for (int kt = 0; kt < 4; ++kt) {
        int cur = kt & 1;
        if (kt < 3) STAGE(cur ^ 1, (kt + 1) * 64);
        #pragma unroll
        for (int kk = 0; kk < 2; ++kk) {
            int kh = kk * 32 + lg * 8;
            f16x8 af[4], bf4[4];
            #pragma unroll
            for (int mi = 0; mi < 4; ++mi) {
                int r = wr * 64 + mi * 16 + lr;
                af[mi] = *(const f16x8*)&As[cur][r][kh ^ ((r & 7) << 3)];
            }
            #pragma unroll
            for (int ni = 0; ni < 4; ++ni) {
                int r = wc * 64 + ni * 16 + lr;
                bf4[ni] = *(const f16x8*)&Bs[cur][r][kh ^ ((r & 7) << 3)];
            }
            #pragma unroll
            for (int mi = 0; mi < 4; ++mi)
                #pragma unroll
                for (int ni = 0; ni < 4; ++ni)
                    acc[mi][ni] = __builtin_amdgcn_mfma_f32_16x16x32_f16(
                        af[mi], bf4[ni], acc[mi][ni], 0, 0, 0);
        }
        __syncthreads();                        // last iter: all LDS reads retired
    }

    int bN = b << 12;

    if (isY) {
        // ---- Yh epilogue: bias add (W2 half) + fp16 store ----
        int colbase = (jt - 32) * 128 + wc * 64;      // wave-uniform 0..448
        bool isY2 = colbase >= 256;
        float bv[4];
        #pragma unroll
        for (int ni = 0; ni < 4; ++ni)
            bv[ni] = isY2 ? bias[colbase - 256 + ni * 16 + lr] : 0.f;
        #pragma unroll
        for (int mi = 0; mi < 4; ++mi)
            #pragma unroll
            for (int r = 0; r < 4; ++r) {
                int p = bN + it * 128 + wr * 64 + mi * 16 + lg * 4 + r;
                #pragma unroll
                for (int ni = 0; ni < 4; ++ni)
                    Yh[(size_t)p * 512 + colbase + ni * 16 + lr] =
                        (_Float16)(acc[mi][ni][r] + bv[ni]);
            }
        return;
    }

    // ---- gram epilogue: per-row top-4 of this wave's 64x64 V block ----
    float sjv[4];
    #pragma unroll
    for (int ni = 0; ni < 4; ++ni)
        sjv[ni] = sq32[bN + jt * 128 + wc * 64 + ni * 16 + lr];

    float* vb = (float*)&As[0][0][0] + w * 4096;        // 16KB per wave
    #pragma unroll
    for (int mi = 0; mi < 4; ++mi)
        #pragma unroll
        for (int ni = 0; ni < 4; ++ni) {
            int c  = ni * 16 + lr;
            int rb = (mi * 16 + lg * 4) ^ ((c & 7) << 3);
            f32x4 vv;
            #pragma unroll
            for (int r = 0; r < 4; ++r)
                vv[r] = sjv[ni] - 2.0f * acc[mi][ni][r];
            *(f32x4*)&vb[c * 64 + rb] = vv;             // V^T, swizzled
        }
    LGKM0();                                            // wave-local visibility
    SCHED0();

    float v0 = INF_F, v1 = INF_F, v2 = INF_F, v3 = INF_F;
    int j0 = 0, j1 = 0, j2 = 0, j3 = 0;
    #pragma unroll
    for (int c = 0; c < 64; ++c) {
        float v = vb[c * 64 + (l ^ ((c & 7) << 3))];
        bool in = v < v3;                               // strict: lowest-c wins ties
        v3 = in ? v : v3;  j3 = in ? c : j3;
        { bool s = v3 < v2; float t = v2; int tj2 = j2;
          v2 = s ? v3 : v2; v3 = s ? t : v3; j2 = s ? j3 : j2; j3 = s ? tj2 : j3; }
        { bool s = v2 < v1; float t = v1; int tj2 = j1;
          v1 = s ? v2 : v1; v2 = s ? t : v2; j1 = s ? j2 : j1; j2 = s ? tj2 : j2; }
        { bool s = v1 < v0; float t = v0; int tj2 = j0;
          v0 = s ? v1 : v0; v1 = s ? t : v1; j0 = s ? j1 : j0; j1 = s ? tj2 : j1; }
    }
    int tj = jt * 2 + wc;
    int q  = bN + it * 128 + wr * 64 + l;
    int jb = jt * 128 + wc * 64;
    size_t ob = ((size_t)q * 64 + tj) * 4;              // [query][tile] layout
    *(float4*)&t4v[ob] = make_float4(v0, v1, v2, v3);
    ushort4 js;
    js.x = (unsigned short)(jb + j0); js.y = (unsigned short)(jb + j1);
    js.z = (unsigned short)(jb + j2); js.w = (unsigned short)(jb + j3);
    *(ushort4*)&t4j[ob] = js;
}

// ---------------- 3) fused collect + fp64 re-rank + weighted-max output ----------------
// block 256 = 4 waves = 4 queries; grid 2048 (8192 waves total).
__global__ void cmf_kernel(const float* __restrict__ t4v,
                           const unsigned short* __restrict__ t4j,
                           const _Float16* __restrict__ xh,
                           const float* __restrict__ sq32,
                           const float* __restrict__ xt,
                           const double* __restrict__ sq64,
                           const _Float16* __restrict__ Yh,
                           float* __restrict__ out) {
    __shared__ float  sv[4][64];
    __shared__ float  sT[4];
    __shared__ int    sj[4][SCAP];
    __shared__ double ds[4][SCAP];
    __shared__ int    snn[4][K_];
    __shared__ float  sww[4][K_];
    int tid = threadIdx.x;
    int wv = tid >> 6, l = tid & 63;
    int q = blockIdx.x * 4 + wv;                  // global query 0..8191
    int b = q >> 12, bN = b << 12;

    // ---- collect phase (coalesced: lane l <-> tile l of query q) ----
    size_t base = ((size_t)q * 64 + l) * 4;
    float4 vf = *(const float4*)&t4v[base];
    ushort4 uf = *(const ushort4*)&t4j[base];
    float v[4] = {vf.x, vf.y, vf.z, vf.w};
    int  j4[4] = {(int)uf.x, (int)uf.y, (int)uf.z, (int)uf.w};

    sv[wv][l] = v[0];
    __syncthreads();
    int rank = 0;
    for (int o = 0; o < 64; ++o) {
        float ov = sv[wv][o];
        rank += (ov < v[0]) || (ov == v[0] && o < l);
    }
    if (rank == 19) sT[wv] = v[0];
    __syncthreads();
    float T5 = sT[wv] + 0.5f;

    int cnt = 0;
    #pragma unroll
    for (int k = 0; k < 4; ++k) cnt += (v[k] <= T5) ? 1 : 0;   // sorted -> prefix
    bool flag = (v[3] <= T5);                     // possible hidden 5th

    int off = cnt;
    #pragma unroll
    for (int s = 1; s < 64; s <<= 1) {
        int n = __shfl_up(off, s);
        if (l >= s) off += n;
    }
    int pos = off - cnt;
    int total = __shfl(off, 63);
    for (int k = 0; k < cnt; ++k)
        if (pos + k < SCAP) sj[wv][pos + k] = j4[k];

    unsigned long long fb = __ballot(flag);
    if (fb != 0ULL) {                             // rare exact-completion path
        const _Float16* qrow = xh + ((size_t)q << 8);
        while (fb) {
            int tf = (int)__ffsll(fb) - 1; fb &= fb - 1;
            int jg = tf * 64 + l;                 // batch-local col
            const _Float16* jrow = xh + (((size_t)(bN + jg)) << 8);
            float dot = 0.f;
            #pragma unroll 4
            for (int c = 0; c < C_; c += 8) {
                f16x8 a = *(const f16x8*)(qrow + c);
                f16x8 bb = *(const f16x8*)(jrow + c);
                #pragma unroll
                for (int e = 0; e < 8; ++e)
                    dot = fmaf((float)a[e], (float)bb[e], dot);
            }
            float vv = sq32[bN + jg] - 2.0f * dot;
            bool dup = false;
            size_t tb = ((size_t)q * 64 + tf) * 4;
            #pragma unroll
            for (int k = 0; k < 4; ++k) dup |= ((int)t4j[tb + k] == jg);
            bool add = (vv <= T5 + 0.0625f) && !dup;
            int o2 = add ? 1 : 0;
            #pragma unroll
            for (int s = 1; s < 64; s <<= 1) {
                int n = __shfl_up(o2, s);
                if (l >= s) o2 += n;
            }
            int p2 = total + o2 - (add ? 1 : 0);
            if (add && p2 < SCAP) sj[wv][p2] = jg;
            total += __shfl(o2, 63);
        }
    }
    if (total > SCAP) total = SCAP;
    LGKM0();                                      // sj visible wave-locally
    SCHED0();

    // ---- merge phase: coalesced row gather + fp64 butterfly dot ----
    int l4 = l << 2;
    float4 qf = *(const float4*)&xt[((size_t)q << 8) + l4];
    for (int cc = 0; cc < total; cc += 2) {
        bool has1 = (cc + 1) < total;
        int n0 = bN + sj[wv][cc];
        int n1 = has1 ? bN + sj[wv][cc + 1] : n0;
        float4 r0 = *(const float4*)&xt[((size_t)n0 << 8) + l4];
        float4 r1 = *(const float4*)&xt[((size_t)n1 << 8) + l4];
        double p0 = fma((double)qf.x, (double)r0.x,
                    fma((double)qf.y, (double)r0.y,
                    fma((double)qf.z, (double)r0.z,
                        (double)qf.w * (double)r0.w)));
        double p1 = fma((double)qf.x, (double)r1.x,
                    fma((double)qf.y, (double)r1.y,
                    fma((double)qf.z, (double)r1.z,
                        (double)qf.w * (double)r1.w)));
        #pragma unroll
        for (int s = 1; s < 64; s <<= 1) {
            p0 += __shfl_xor(p0, s);
            p1 += __shfl_xor(p1, s);
        }
        if (l == 0) {
            ds[wv][cc] = sq64[n0] - 2.0 * p0;
            if (has1) ds[wv][cc + 1] = sq64[n1] - 2.0 * p1;
        }
    }
    LGKM0();
    SCHED0();

    // ---- rank-count top-16 -> per-wave LDS (n, w) ----
    double rdm = sqrt(sq64[q]);
    for (int p = l; p < total; p += 64) {
        double d = ds[wv][p];
        int rk = 0;
        for (int o = 0; o < total; ++o) {
            double od = ds[wv][o];
            rk += (od < d) || (od == d && o < p);
        }
        if (rk < K_) {
            int n = bN + sj[wv][p];
            double sqn = sq64[n];
            double dot = 0.5 * (sqn - d);
            double w = dot / (sqrt(sqn) * rdm);
            snn[wv][rk] = n;
            sww[wv][rk] = (float)w;
        }
    }
    LGKM0();
    SCHED0();

    // ---- weighted-max epilogue: lane l owns channels 4l..4l+3 ----
    f16x4 y2h = *(const f16x4*)&Yh[(size_t)q * 512 + 256 + l4];
    float y2[4] = {(float)y2h[0], (float)y2h[1], (float)y2h[2], (float)y2h[3]};
    float acc[4] = {-INF_F, -INF_F, -INF_F, -INF_F};
    #pragma unroll
    for (int k = 0; k < K_; ++k) {
        int n = snn[wv][k];
        float wk = sww[wv][k];
        f16x4 y1h = *(const f16x4*)&Yh[(size_t)n * 512 + l4];
        #pragma unroll
        for (int j = 0; j < 4; ++j)
            acc[j] = fmaxf(acc[j], wk * ((float)y1h[j] + y2[j]));
    }
    int i = q & 4095;
    float* ob = out + ((size_t)(b << 8) + l4) * N_ + i;
    #pragma unroll
    for (int j = 0; j < 4; ++j)
        ob[(size_t)j * N_] = acc[j];
}

extern "C" void kernel_launch(void* const* d_in, const int* in_sizes, int n_in,
                              void* d_out, int out_size, void* d_ws, size_t ws_size,
                              hipStream_t stream) {
    const float* x    = (const float*)d_in[0];
    const float* W    = (const float*)d_in[1];
    const float* bias = (const float*)d_in[2];
    float* out = (float*)d_out;

    float* ws = (float*)d_ws;
    size_t off = 0;
    float*  sq32 = ws + off;            off += 8192;
    double* sq64 = (double*)(ws + off); off += 16384;
    float*  xt   = ws + off;            off += 2097152;    // 8 MB
    _Float16* xh = (_Float16*)(ws + off); off += 1048576;  // 4 MB (2M halfs)
    float*  t4v  = ws + off;            off += 2097152;    // 8192 x 64 x 4 f32
    unsigned short* t4j = (unsigned short*)(ws + off); off += 1048576;
    _Float16* Wh = (_Float16*)(ws + off); off += 65536;    // 512x256 halfs
    _Float16* Yh = (_Float16*)(ws + off); off += 1048576;  // 8192x512 halfs (8MB)

    prep_kernel<<<dim3(64, 1, 3), 256, 0, stream>>>(x, xt, xh, W, Wh, sq32, sq64);

    distyh_kernel<<<dim3(36, 32, 2), 256, 0, stream>>>(xh, Wh, sq32, bias,
                                                       t4v, t4j, Yh);
    cmf_kernel<<<2048, 256, 0, stream>>>(t4v, t4j, xh, sq32, xt, sq64, Yh, out);
}

// Round 23
// 138.268 us; speedup vs baseline: 1.0128x; 1.0128x over previous
//
#include <hip/hip_runtime.h>

// NeighConv: B=2, C=256, N=4096, K=16  -- best-measured configuration (R21).
// Pipeline (SINGLE gram sweep; yh fused into dist; final fused into collect):
//  1) prep_kernel:    xt[p][c] fp32 + xh[p][c] fp16; z==2 branch: Wh fp16
//  2) sq2_kernel:     sq32/sq64 from xt rows (coalesced, wave per point)
//  3) distyh_kernel:  double-buffered 64KB LDS; jt<32: MFMA gram tile + top-4
//                     epilogue (V^T->LDS scan); jt>=32: K-loop vs Wh -> Yh
//  4) cmf_kernel:     per query (one wave): threshold-collect -> fp64 re-rank
//                     -> top-16+weights in LDS -> weighted-max epilogue -> out
// Structural note: distyh delivers ~276 TF = this 2-barrier 128^2 structure's
// calibrated throughput at this work size (m102); 12 structural variants were
// measured neutral or worse. Further gains require an 8-phase 256^2 rewrite.

#define B_ 2
#define C_ 256
#define N_ 4096
#define K_ 16
#define SCAP 128
#define INF_F 3.0e38f

typedef _Float16 f16x8 __attribute__((ext_vector_type(8)));
typedef _Float16 f16x4 __attribute__((ext_vector_type(4)));
typedef float    f32x4 __attribute__((ext_vector_type(4)));

// async global->LDS, 16B per lane; LDS dest wave-uniform base + lane*16
#define GL16(gp, lp)                                                        \
    __builtin_amdgcn_global_load_lds(                                       \
        (const __attribute__((address_space(1))) void*)(gp),                \
        (__attribute__((address_space(3))) void*)(lp), 16, 0, 0)

#define LGKM0()  asm volatile("s_waitcnt lgkmcnt(0)" ::: "memory")
#define SCHED0() __builtin_amdgcn_sched_barrier(0)

// ---------------- 1) prep: transpose x -> xt/xh; z==2: W -> Wh ----------------
__global__ void prep_kernel(const float* __restrict__ x, float* __restrict__ xt,
                            _Float16* __restrict__ xh,
                            const float* __restrict__ W, _Float16* __restrict__ Wh) {
    int tid = threadIdx.x;
    if (blockIdx.z == 2) {                            // Wh branch: 2 rows/block
        int r0 = ((blockIdx.y << 6) + blockIdx.x) << 1;
        #pragma unroll
        for (int u = 0; u < 2; ++u) {
            int r = r0 + u;
            float v = (r < 256) ? W[(size_t)r * 512 + tid]
                                : W[(size_t)(r - 256) * 512 + 256 + tid];
            Wh[(size_t)r * 256 + tid] = (_Float16)v;
        }
        return;
    }
    __shared__ float tile[64][65];
    int i0 = blockIdx.x * 64;
    int c0 = blockIdx.y * 64;
    int b  = blockIdx.z;
    const float* xb = x + ((size_t)b << 20);
    int tx = tid & 63, tyy = tid >> 6;
    for (int r = tyy; r < 64; r += 4)
        tile[r][tx] = xb[(size_t)(c0 + r) * N_ + i0 + tx];
    __syncthreads();
    float*    xtb = xt + ((size_t)b << 20);
    _Float16* xhb = xh + ((size_t)b << 20);
    for (int r = tyy; r < 64; r += 4) {
        float v = tile[tx][r];
        xtb[(size_t)(i0 + r) * C_ + c0 + tx] = v;
        xhb[(size_t)(i0 + r) * C_ + c0 + tx] = (_Float16)v;
    }
}

// ---------------- 2) squared norms from xt (coalesced, wave per point) ----------------
__global__ void sq2_kernel(const float* __restrict__ xt,
                           float* __restrict__ sq32, double* __restrict__ sq64) {
    int tid = threadIdx.x;
    int wv = tid >> 6, l = tid & 63;
    int p = (blockIdx.x << 2) + wv;                   // 0..8191
    float4 v = *(const float4*)&xt[((size_t)p << 8) + (l << 2)];
    double s = fma((double)v.x, (double)v.x,
               fma((double)v.y, (double)v.y,
               fma((double)v.z, (double)v.z,
                   (double)v.w * (double)v.w)));
    #pragma unroll
    for (int m = 1; m < 64; m <<= 1) s += __shfl_xor(s, m);
    if (l == 0) { sq64[p] = s; sq32[p] = (float)s; }
}

// ---------------- 3) fused gram sweep + Yh GEMM (double-buffered, 64KB LDS) ----------------
// grid (36, 32, 2). jt<32: gram tile (128i x 128j) + per-tile top-4 epilogue.
// jt>=32: B = Wh rows (jt-32)*128.., epilogue = bias add + Yh store.
// Conflict-free swizzle (128B rows): byte cb of row r at cb ^ ((r&7)<<4),
// applied to the global SOURCE (gload_lds writes linearly) and to ds_reads.
__launch_bounds__(256, 2)
__global__ void distyh_kernel(const _Float16* __restrict__ xh,
                              const _Float16* __restrict__ Wh,
                              const float* __restrict__ sq32,
                              const float* __restrict__ bias,
                              float* __restrict__ t4v,
                              unsigned short* __restrict__ t4j,
                              _Float16* __restrict__ Yh) {
    __shared__ alignas(16) _Float16 As[2][128][64];
    __shared__ alignas(16) _Float16 Bs[2][128][64];

    int jt = blockIdx.x, it = blockIdx.y, b = blockIdx.z;
    int tid = threadIdx.x;
    int w = tid >> 6, l = tid & 63;
    int wr = w >> 1, wc = w & 1;
    int lr = l & 15, lg = l >> 4;
    const _Float16* xb = xh + ((size_t)b << 20);
    bool isY = jt >= 32;
    int rA0 = it * 128;
    const _Float16* bsrc = isY ? (Wh + (size_t)(jt - 32) * 128 * C_)
                               : (xb + (size_t)(jt * 128) * C_);

    int rsub = l >> 3;                          // 0..7
    int cbyte = (l & 7) << 4;                   // 0..112 bytes

    auto STAGE = [&](int bf, int k0) {
        #pragma unroll
        for (int tt = 0; tt < 4; ++tt) {
            int rloc = w * 32 + tt * 8 + rsub;                 // 0..127
            int srch = (cbyte ^ ((rloc & 7) << 4)) >> 1;       // halfs
            GL16(xb + (size_t)(rA0 + rloc) * C_ + k0 + srch, &As[bf][w * 32 + tt * 8][0]);
            GL16(bsrc + (size_t)rloc * C_ + k0 + srch, &Bs[bf][w * 32 + tt * 8][0]);
        }
    };

    f32x4 acc[4][4];
    #pragma unroll
    for (int mi = 0; mi < 4; ++mi)
        #pragma unroll
        for (int ni = 0; ni < 4; ++ni)
            acc[mi][ni] = (f32x4){0.f, 0.f, 0.f, 0.f};

    STAGE(0, 0);
    __syncthreads();
    #pragma unroll
    for (int kt = 0; kt < 4; ++kt) {
        int cur = kt & 1;
        if (kt < 3) STAGE(cur ^ 1, (kt + 1) * 64);
        #pragma unroll
        for (int kk = 0; kk < 2; ++kk) {
            int kh = kk * 32 + lg * 8;
            f16x8 af[4], bf4[4];
            #pragma unroll
            for (int mi = 0; mi < 4; ++mi) {
                int r = wr * 64 + mi * 16 + lr;
                af[mi] = *(const f16x8*)&As[cur][r][kh ^ ((r & 7) << 3)];
            }
            #pragma unroll
            for (int ni = 0; ni < 4; ++ni) {
                int r = wc * 64 + ni * 16 + lr;
                bf4[ni] = *(const f16x8*)&Bs[cur][r][kh ^ ((r & 7) << 3)];
            }
            #pragma unroll
            for (int mi = 0; mi < 4; ++mi)
                #pragma unroll
                for (int ni = 0; ni < 4; ++ni)
                    acc[mi][ni] = __builtin_amdgcn_mfma_f32_16x16x32_f16(
                        af[mi], bf4[ni], acc[mi][ni], 0, 0, 0);
        }
        __syncthreads();                        // last iter: all LDS reads retired
    }

    int bN = b << 12;

    if (isY) {
        // ---- Yh epilogue: bias add (W2 half) + fp16 store ----
        int colbase = (jt - 32) * 128 + wc * 64;      // wave-uniform 0..448
        bool isY2 = colbase >= 256;
        float bv[4];
        #pragma unroll
        for (int ni = 0; ni < 4; ++ni)
            bv[ni] = isY2 ? bias[colbase - 256 + ni * 16 + lr] : 0.f;
        #pragma unroll
        for (int mi = 0; mi < 4; ++mi)
            #pragma unroll
            for (int r = 0; r < 4; ++r) {
                int p = bN + it * 128 + wr * 64 + mi * 16 + lg * 4 + r;
                #pragma unroll
                for (int ni = 0; ni < 4; ++ni)
                    Yh[(size_t)p * 512 + colbase + ni * 16 + lr] =
                        (_Float16)(acc[mi][ni][r] + bv[ni]);
            }
        return;
    }

    // ---- gram epilogue: per-row top-4 of this wave's 64x64 V block ----
    float sjv[4];
    #pragma unroll
    for (int ni = 0; ni < 4; ++ni)
        sjv[ni] = sq32[bN + jt * 128 + wc * 64 + ni * 16 + lr];

    float* vb = (float*)&As[0][0][0] + w * 4096;        // 16KB per wave
    #pragma unroll
    for (int mi = 0; mi < 4; ++mi)
        #pragma unroll
        for (int ni = 0; ni < 4; ++ni) {
            int c  = ni * 16 + lr;
            int rb = (mi * 16 + lg * 4) ^ ((c & 7) << 3);
            f32x4 vv;
            #pragma unroll
            for (int r = 0; r < 4; ++r)
                vv[r] = sjv[ni] - 2.0f * acc[mi][ni][r];
            *(f32x4*)&vb[c * 64 + rb] = vv;             // V^T, swizzled
        }
    LGKM0();                                            // wave-local visibility
    SCHED0();

    float v0 = INF_F, v1 = INF_F, v2 = INF_F, v3 = INF_F;
    int j0 = 0, j1 = 0, j2 = 0, j3 = 0;
    #pragma unroll
    for (int c = 0; c < 64; ++c) {
        float v = vb[c * 64 + (l ^ ((c & 7) << 3))];
        bool in = v < v3;                               // strict: lowest-c wins ties
        v3 = in ? v : v3;  j3 = in ? c : j3;
        { bool s = v3 < v2; float t = v2; int tj2 = j2;
          v2 = s ? v3 : v2; v3 = s ? t : v3; j2 = s ? j3 : j2; j3 = s ? tj2 : j3; }
        { bool s = v2 < v1; float t = v1; int tj2 = j1;
          v1 = s ? v2 : v1; v2 = s ? t : v2; j1 = s ? j2 : j1; j2 = s ? tj2 : j2; }
        { bool s = v1 < v0; float t = v0; int tj2 = j0;
          v0 = s ? v1 : v0; v1 = s ? t : v1; j0 = s ? j1 : j0; j1 = s ? tj2 : j1; }
    }
    int tj = jt * 2 + wc;
    int q  = bN + it * 128 + wr * 64 + l;
    int jb = jt * 128 + wc * 64;
    size_t ob = ((size_t)q * 64 + tj) * 4;              // [query][tile] layout
    *(float4*)&t4v[ob] = make_float4(v0, v1, v2, v3);
    ushort4 js;
    js.x = (unsigned short)(jb + j0); js.y = (unsigned short)(jb + j1);
    js.z = (unsigned short)(jb + j2); js.w = (unsigned short)(jb + j3);
    *(ushort4*)&t4j[ob] = js;
}

// ---------------- 4) fused collect + fp64 re-rank + weighted-max output ----------------
// block 256 = 4 waves = 4 queries; grid 2048 (8192 waves total).
__global__ void cmf_kernel(const float* __restrict__ t4v,
                           const unsigned short* __restrict__ t4j,
                           const _Float16* __restrict__ xh,
                           const float* __restrict__ sq32,
                           const float* __restrict__ xt,
                           const double* __restrict__ sq64,
                           const _Float16* __restrict__ Yh,
                           float* __restrict__ out) {
    __shared__ float  sv[4][64];
    __shared__ float  sT[4];
    __shared__ int    sj[4][SCAP];
    __shared__ double ds[4][SCAP];
    __shared__ int    snn[4][K_];
    __shared__ float  sww[4][K_];
    int tid = threadIdx.x;
    int wv = tid >> 6, l = tid & 63;
    int q = blockIdx.x * 4 + wv;                  // global query 0..8191
    int b = q >> 12, bN = b << 12;

    // ---- collect phase (coalesced: lane l <-> tile l of query q) ----
    size_t base = ((size_t)q * 64 + l) * 4;
    float4 vf = *(const float4*)&t4v[base];
    ushort4 uf = *(const ushort4*)&t4j[base];
    float v[4] = {vf.x, vf.y, vf.z, vf.w};
    int  j4[4] = {(int)uf.x, (int)uf.y, (int)uf.z, (int)uf.w};

    sv[wv][l] = v[0];
    __syncthreads();
    int rank = 0;
    for (int o = 0; o < 64; ++o) {
        float ov = sv[wv][o];
        rank += (ov < v[0]) || (ov == v[0] && o < l);
    }
    if (rank == 19) sT[wv] = v[0];
    __syncthreads();
    float T5 = sT[wv] + 0.5f;

    int cnt = 0;
    #pragma unroll
    for (int k = 0; k < 4; ++k) cnt += (v[k] <= T5) ? 1 : 0;   // sorted -> prefix
    bool flag = (v[3] <= T5);                     // possible hidden 5th

    int off = cnt;
    #pragma unroll
    for (int s = 1; s < 64; s <<= 1) {
        int n = __shfl_up(off, s);
        if (l >= s) off += n;
    }
    int pos = off - cnt;
    int total = __shfl(off, 63);
    for (int k = 0; k < cnt; ++k)
        if (pos + k < SCAP) sj[wv][pos + k] = j4[k];

    unsigned long long fb = __ballot(flag);
    if (fb != 0ULL) {                             // rare exact-completion path
        const _Float16* qrow = xh + ((size_t)q << 8);
        while (fb) {
            int tf = (int)__ffsll(fb) - 1; fb &= fb - 1;
            int jg = tf * 64 + l;                 // batch-local col
            const _Float16* jrow = xh + (((size_t)(bN + jg)) << 8);
            float dot = 0.f;
            #pragma unroll 4
            for (int c = 0; c < C_; c += 8) {
                f16x8 a = *(const f16x8*)(qrow + c);
                f16x8 bb = *(const f16x8*)(jrow + c);
                #pragma unroll
                for (int e = 0; e < 8; ++e)
                    dot = fmaf((float)a[e], (float)bb[e], dot);
            }
            float vv = sq32[bN + jg] - 2.0f * dot;
            bool dup = false;
            size_t tb = ((size_t)q * 64 + tf) * 4;
            #pragma unroll
            for (int k = 0; k < 4; ++k) dup |= ((int)t4j[tb + k] == jg);
            bool add = (vv <= T5 + 0.0625f) && !dup;
            int o2 = add ? 1 : 0;
            #pragma unroll
            for (int s = 1; s < 64; s <<= 1) {
                int n = __shfl_up(o2, s);
                if (l >= s) o2 += n;
            }
            int p2 = total + o2 - (add ? 1 : 0);
            if (add && p2 < SCAP) sj[wv][p2] = jg;
            total += __shfl(o2, 63);
        }
    }
    if (total > SCAP) total = SCAP;
    LGKM0();                                      // sj visible wave-locally
    SCHED0();

    // ---- merge phase: coalesced row gather + fp64 butterfly dot ----
    int l4 = l << 2;
    float4 qf = *(const float4*)&xt[((size_t)q << 8) + l4];
    for (int cc = 0; cc < total; cc += 2) {
        bool has1 = (cc + 1) < total;
        int n0 = bN + sj[wv][cc];
        int n1 = has1 ? bN + sj[wv][cc + 1] : n0;
        float4 r0 = *(const float4*)&xt[((size_t)n0 << 8) + l4];
        float4 r1 = *(const float4*)&xt[((size_t)n1 << 8) + l4];
        double p0 = fma((double)qf.x, (double)r0.x,
                    fma((double)qf.y, (double)r0.y,
                    fma((double)qf.z, (double)r0.z,
                        (double)qf.w * (double)r0.w)));
        double p1 = fma((double)qf.x, (double)r1.x,
                    fma((double)qf.y, (double)r1.y,
                    fma((double)qf.z, (double)r1.z,
                        (double)qf.w * (double)r1.w)));
        #pragma unroll
        for (int s = 1; s < 64; s <<= 1) {
            p0 += __shfl_xor(p0, s);
            p1 += __shfl_xor(p1, s);
        }
        if (l == 0) {
            ds[wv][cc] = sq64[n0] - 2.0 * p0;
            if (has1) ds[wv][cc + 1] = sq64[n1] - 2.0 * p1;
        }
    }
    LGKM0();
    SCHED0();

    // ---- rank-count top-16 -> per-wave LDS (n, w) ----
    double rdm = sqrt(sq64[q]);
    for (int p = l; p < total; p += 64) {
        double d = ds[wv][p];
        int rk = 0;
        for (int o = 0; o < total; ++o) {
            double od = ds[wv][o];
            rk += (od < d) || (od == d && o < p);
        }
        if (rk < K_) {
            int n = bN + sj[wv][p];
            double sqn = sq64[n];
            double dot = 0.5 * (sqn - d);
            double w = dot / (sqrt(sqn) * rdm);
            snn[wv][rk] = n;
            sww[wv][rk] = (float)w;
        }
    }
    LGKM0();
    SCHED0();

    // ---- weighted-max epilogue: lane l owns channels 4l..4l+3 ----
    f16x4 y2h = *(const f16x4*)&Yh[(size_t)q * 512 + 256 + l4];
    float y2[4] = {(float)y2h[0], (float)y2h[1], (float)y2h[2], (float)y2h[3]};
    float acc[4] = {-INF_F, -INF_F, -INF_F, -INF_F};
    #pragma unroll
    for (int k = 0; k < K_; ++k) {
        int n = snn[wv][k];
        float wk = sww[wv][k];
        f16x4 y1h = *(const f16x4*)&Yh[(size_t)n * 512 + l4];
        #pragma unroll
        for (int j = 0; j < 4; ++j)
            acc[j] = fmaxf(acc[j], wk * ((float)y1h[j] + y2[j]));
    }
    int i = q & 4095;
    float* ob = out + ((size_t)(b << 8) + l4) * N_ + i;
    #pragma unroll
    for (int j = 0; j < 4; ++j)
        ob[(size_t)j * N_] = acc[j];
}

extern "C" void kernel_launch(void* const* d_in, const int* in_sizes, int n_in,
                              void* d_out, int out_size, void* d_ws, size_t ws_size,
                              hipStream_t stream) {
    const float* x    = (const float*)d_in[0];
    const float* W    = (const float*)d_in[1];
    const float* bias = (const float*)d_in[2];
    float* out = (float*)d_out;

    float* ws = (float*)d_ws;
    size_t off = 0;
    float*  sq32 = ws + off;            off += 8192;
    double* sq64 = (double*)(ws + off); off += 16384;
    float*  xt   = ws + off;            off += 2097152;    // 8 MB
    _Float16* xh = (_Float16*)(ws + off); off += 1048576;  // 4 MB (2M halfs)
    float*  t4v  = ws + off;            off += 2097152;    // 8192 x 64 x 4 f32
    unsigned short* t4j = (unsigned short*)(ws + off); off += 1048576;
    _Float16* Wh = (_Float16*)(ws + off); off += 65536;    // 512x256 halfs
    _Float16* Yh = (_Float16*)(ws + off); off += 1048576;  // 8192x512 halfs (8MB)

    prep_kernel<<<dim3(64, 4, 3), 256, 0, stream>>>(x, xt, xh, W, Wh);
    sq2_kernel<<<2048, 256, 0, stream>>>(xt, sq32, sq64);

    distyh_kernel<<<dim3(36, 32, 2), 256, 0, stream>>>(xh, Wh, sq32, bias,
                                                       t4v, t4j, Yh);
    cmf_kernel<<<2048, 256, 0, stream>>>(t4v, t4j, xh, sq32, xt, sq64, Yh, out);
}